// Round 9
// baseline (829.361 us; speedup 1.0000x reference)
//
#include <hip/hip_runtime.h>
#include <hip/hip_bf16.h>
#include <math.h>

#define F_DIM 128
#define B_GRAPHS 64
#define AGG_NODES 32   // nodes per agg block
#define AGG_NPW 4      // nodes per wave (8 waves)

__device__ __forceinline__ float lrelu(float v, float s) {
    return v > 0.f ? v : s * v;
}

__device__ __forceinline__ int lower_bound_i(const int* __restrict__ a, int n, int v) {
    int lo = 0, hi = n;
    while (lo < hi) {
        int mid = (lo + hi) >> 1;
        if (a[mid] < v) lo = mid + 1; else hi = mid;
    }
    return lo;
}

// ---------------------------------------------------------------------------
// edge counts per dst, both channels (blockIdx.y = channel)
__global__ void count2_k(const int* __restrict__ ei0, const int* __restrict__ ei1,
                         int* __restrict__ c0, int* __restrict__ c1, int E) {
    const int* ei = blockIdx.y ? ei1 : ei0;
    int* cnt = blockIdx.y ? c1 : c0;
    int i = blockIdx.x * blockDim.x + threadIdx.x;
    if (i < E) atomicAdd(cnt + ei[E + i], 1);
}

// ---------------------------------------------------------------------------
// chunked exclusive scan over (cnt[i]+1), one block per channel
__global__ __launch_bounds__(1024) void scan2_k(const int* __restrict__ c0,
                                                const int* __restrict__ c1,
                                                int* __restrict__ s0, int* __restrict__ s1,
                                                int n, int tot) {
    const int* cnt = blockIdx.x ? c1 : c0;
    int* start = blockIdx.x ? s1 : s0;
    __shared__ int ssum[1024];
    int t = threadIdx.x;
    int chunk = (n + 1023) / 1024;
    int lo = t * chunk, hi = min(lo + chunk, n);
    int s = 0;
    for (int i = lo; i < hi; ++i) s += cnt[i] + 1;
    ssum[t] = s;
    __syncthreads();
    for (int offs = 1; offs < 1024; offs <<= 1) {
        int v = (t >= offs) ? ssum[t - offs] : 0;
        __syncthreads();
        ssum[t] += v;
        __syncthreads();
    }
    int excl = (t == 0) ? 0 : ssum[t - 1];
    for (int i = lo; i < hi; ++i) {
        start[i] = excl;
        excl += cnt[i] + 1;
    }
    if (t == 1023) start[n] = tot;
}

// ---------------------------------------------------------------------------
// ch0 GEMM fused with BOTH channels' CSR scatter (r6 arrangement, 152us)
__global__ __launch_bounds__(256) void gemm2_bias_scatter(
        const float* __restrict__ A,
        const float* __restrict__ Wl, const float* __restrict__ bl,
        const float* __restrict__ Wr, const float* __restrict__ br,
        float* __restrict__ Cl, float* __restrict__ Cr, int n,
        const int* __restrict__ ei0, const int* __restrict__ ei1,
        const int* __restrict__ st0, const int* __restrict__ st1,
        int* __restrict__ c0, int* __restrict__ c1,
        int* __restrict__ ss0, int* __restrict__ ss1,
        int E, int tot, int ipb) {
    // ---- scatter prologue: issue atomics, keep results in regs ----
    int base = blockIdx.x * ipb;
    int lim = min(base + ipb, 2 * tot);
    int pos_0 = -1, pos_1 = -1, pos_2 = -1;
    int src_0 = 0, src_1 = 0, src_2 = 0;
    int* ssp_0 = ss0; int* ssp_1 = ss0; int* ssp_2 = ss0;
    #pragma unroll
    for (int q = 0; q < 3; ++q) {
        int it = base + q * 256 + (int)threadIdx.x;
        if (it < lim) {
            int ch = (it >= tot) ? 1 : 0;
            int local = it - (ch ? tot : 0);
            const int* ei = ch ? ei1 : ei0;
            const int* st = ch ? st1 : st0;
            int* cnt = ch ? c1 : c0;
            int* ss = ch ? ss1 : ss0;
            int pos, src;
            if (local < n) {               // self loop -> slot 0
                pos = st[local];
                src = local;
            } else {
                int j = local - n;
                int dst = ei[E + j];
                src = ei[j];
                int o = atomicAdd(cnt + dst, -1);   // o in [deg..1]
                pos = st[dst] + o;
            }
            if (q == 0) { pos_0 = pos; src_0 = src; ssp_0 = ss; }
            if (q == 1) { pos_1 = pos; src_1 = src; ssp_1 = ss; }
            if (q == 2) { pos_2 = pos; src_2 = src; ssp_2 = ss; }
        }
    }
    for (int it = base + 768 + (int)threadIdx.x; it < lim; it += 256) {
        int ch = (it >= tot) ? 1 : 0;
        int local = it - (ch ? tot : 0);
        const int* ei = ch ? ei1 : ei0;
        const int* st = ch ? st1 : st0;
        int* cnt = ch ? c1 : c0;
        int* ss = ch ? ss1 : ss0;
        if (local < n) ss[st[local]] = local;
        else {
            int j = local - n;
            int dst = ei[E + j];
            int o = atomicAdd(cnt + dst, -1);
            ss[st[dst] + o] = ei[j];
        }
    }

    // ---- GEMM ----
    __shared__ float As[16][F_DIM];
    int row0 = blockIdx.x * 16;
    for (int i = threadIdx.x; i < 16 * F_DIM; i += 256) {
        int r = i >> 7, c = i & 127;
        int gr = row0 + r;
        As[r][c] = (gr < n) ? A[(size_t)gr * F_DIM + c] : 0.f;
    }
    __syncthreads();
    int c = threadIdx.x & 127;
    int rg = (threadIdx.x >> 7) * 8;
    float accl[8] = {0.f, 0.f, 0.f, 0.f, 0.f, 0.f, 0.f, 0.f};
    float accr[8] = {0.f, 0.f, 0.f, 0.f, 0.f, 0.f, 0.f, 0.f};
    for (int k = 0; k < F_DIM; k += 4) {
        float wl0 = Wl[(k + 0) * F_DIM + c];
        float wl1 = Wl[(k + 1) * F_DIM + c];
        float wl2 = Wl[(k + 2) * F_DIM + c];
        float wl3 = Wl[(k + 3) * F_DIM + c];
        float wr0 = Wr[(k + 0) * F_DIM + c];
        float wr1 = Wr[(k + 1) * F_DIM + c];
        float wr2 = Wr[(k + 2) * F_DIM + c];
        float wr3 = Wr[(k + 3) * F_DIM + c];
        #pragma unroll
        for (int j = 0; j < 8; ++j) {
            float4 a = *(const float4*)&As[rg + j][k];
            accl[j] += a.x * wl0 + a.y * wl1 + a.z * wl2 + a.w * wl3;
            accr[j] += a.x * wr0 + a.y * wr1 + a.z * wr2 + a.w * wr3;
        }
    }
    #pragma unroll
    for (int j = 0; j < 8; ++j) {
        int r = row0 + rg + j;
        if (r < n) {
            Cl[(size_t)r * F_DIM + c] = accl[j] + bl[c];
            Cr[(size_t)r * F_DIM + c] = accr[j] + br[c];
        }
    }

    // ---- scatter epilogue ----
    if (pos_0 >= 0) ssp_0[pos_0] = src_0;
    if (pos_1 >= 0) ssp_1[pos_1] = src_1;
    if (pos_2 >= 0) ssp_2[pos_2] = src_2;
}

// ---------------------------------------------------------------------------
// plain dual GEMM for channel 1
__global__ __launch_bounds__(256) void gemm2_bias(
        const float* __restrict__ A,
        const float* __restrict__ Wl, const float* __restrict__ bl,
        const float* __restrict__ Wr, const float* __restrict__ br,
        float* __restrict__ Cl, float* __restrict__ Cr, int n) {
    __shared__ float As[16][F_DIM];
    int row0 = blockIdx.x * 16;
    for (int i = threadIdx.x; i < 16 * F_DIM; i += 256) {
        int r = i >> 7, c = i & 127;
        int gr = row0 + r;
        As[r][c] = (gr < n) ? A[(size_t)gr * F_DIM + c] : 0.f;
    }
    __syncthreads();
    int c = threadIdx.x & 127;
    int rg = (threadIdx.x >> 7) * 8;
    float accl[8] = {0.f, 0.f, 0.f, 0.f, 0.f, 0.f, 0.f, 0.f};
    float accr[8] = {0.f, 0.f, 0.f, 0.f, 0.f, 0.f, 0.f, 0.f};
    for (int k = 0; k < F_DIM; k += 4) {
        float wl0 = Wl[(k + 0) * F_DIM + c];
        float wl1 = Wl[(k + 1) * F_DIM + c];
        float wl2 = Wl[(k + 2) * F_DIM + c];
        float wl3 = Wl[(k + 3) * F_DIM + c];
        float wr0 = Wr[(k + 0) * F_DIM + c];
        float wr1 = Wr[(k + 1) * F_DIM + c];
        float wr2 = Wr[(k + 2) * F_DIM + c];
        float wr3 = Wr[(k + 3) * F_DIM + c];
        #pragma unroll
        for (int j = 0; j < 8; ++j) {
            float4 a = *(const float4*)&As[rg + j][k];
            accl[j] += a.x * wl0 + a.y * wl1 + a.z * wl2 + a.w * wl3;
            accr[j] += a.x * wr0 + a.y * wr1 + a.z * wr2 + a.w * wr3;
        }
    }
    #pragma unroll
    for (int j = 0; j < 8; ++j) {
        int r = row0 + rg + j;
        if (r < n) {
            Cl[(size_t)r * F_DIM + c] = accl[j] + bl[c];
            Cr[(size_t)r * F_DIM + c] = accr[j] + br[c];
        }
    }
}

// ---------------------------------------------------------------------------
// v9 aggregation: block = 32 consecutive dst nodes, 8 waves, wave owns 4
// nodes (their CSR spans are contiguous). xr staged ONCE in LDS (transposed
// [ch][node], stride 33 -> 2-way banks = free). Accumulators in LDS, same
// layout, exclusively owned per wave -> no atomics. Lane owns channels
// {l, l+64} (stride-1 per bank). 4-edge batches with index prefetch (the
// r8 structure that saturates ~1.87 TB/s miss BW). No-max softmax (logits
// bounded ~1.2 by construction; proven absmax 0.0 in r5-r8).
__global__ __launch_bounds__(512) void gat_agg_v9(
        const float* __restrict__ xl, const float* __restrict__ xr,
        const float* __restrict__ att, const float* __restrict__ bias,
        const int* __restrict__ start, const int* __restrict__ ss,
        const int* __restrict__ batch, float* __restrict__ pool, int n) {
    __shared__ float xrs[F_DIM][AGG_NODES + 1];
    __shared__ float acc[F_DIM][AGG_NODES + 1];
    __shared__ float dvs[4][AGG_NODES + 8];
    __shared__ int gb[AGG_NODES];

    int base = blockIdx.x * AGG_NODES;
    int nodes = min(AGG_NODES, n - base);
    int tid = threadIdx.x;

    for (int i = tid; i < F_DIM * (AGG_NODES + 1); i += 512) ((float*)acc)[i] = 0.f;
    if (tid < 4 * (AGG_NODES + 8)) ((float*)dvs)[tid] = 0.f;
    if (tid < nodes) gb[tid] = batch[base + tid];
    {   // stage xr transposed: thread (col, r0) covers rows r0, r0+4, ...
        int col = tid & 127, r0 = tid >> 7;
        for (int row = r0; row < nodes; row += 4)
            xrs[col][row] = xr[(size_t)(base + row) * F_DIM + col];
    }
    __syncthreads();

    int wv = tid >> 6, l = tid & 63;
    float at0 = att[l], at1 = att[64 + l];

    int nb = wv * AGG_NPW;
    int lim = min(AGG_NPW, nodes - nb);
    if (lim > 0) {
        int b0 = start[base + nb];
        int b1 = start[base + nb + min(1, lim)];
        int b2 = start[base + nb + min(2, lim)];
        int b3 = start[base + nb + min(3, lim)];
        int iend = start[base + nb + lim];

        int nsrc[4];
        #pragma unroll
        for (int q = 0; q < 4; ++q) nsrc[q] = ss[min(b0 + q, iend - 1)];

        for (int i = b0; i < iend; i += 4) {
            int csrc[4];
            #pragma unroll
            for (int q = 0; q < 4; ++q) csrc[q] = nsrc[q];
            #pragma unroll
            for (int q = 0; q < 4; ++q) nsrc[q] = ss[min(i + 4 + q, iend - 1)];
            float g0[4], g1[4];
            #pragma unroll
            for (int q = 0; q < 4; ++q) {
                const float* p = xl + (size_t)csrc[q] * F_DIM;
                g0[q] = p[l];
                g1[q] = p[64 + l];
            }
            #pragma unroll
            for (int q = 0; q < 4; ++q) {
                int it = i + q;
                if (it >= iend) break;          // wave-uniform
                int k = (it >= b1) + (it >= b2) + (it >= b3);
                int dl = nb + k;
                float pa = lrelu(g0[q] + xrs[l][dl], 0.2f) * at0;
                float pb = lrelu(g1[q] + xrs[64 + l][dl], 0.2f) * at1;
                // reduce over each 32-lane half (head = ch>>5)
                pa += __shfl_xor(pa, 1);  pb += __shfl_xor(pb, 1);
                pa += __shfl_xor(pa, 2);  pb += __shfl_xor(pb, 2);
                pa += __shfl_xor(pa, 4);  pb += __shfl_xor(pb, 4);
                pa += __shfl_xor(pa, 8);  pb += __shfl_xor(pb, 8);
                pa += __shfl_xor(pa, 16); pb += __shfl_xor(pb, 16);
                float wa = __expf(pa);
                float wb = __expf(pb);
                acc[l][dl]      += wa * g0[q];
                acc[64 + l][dl] += wb * g1[q];
                if ((l & 31) == 0) {
                    dvs[l >> 5][dl]       += wa;
                    dvs[2 + (l >> 5)][dl] += wb;
                }
            }
        }
    }
    __syncthreads();

    // finalize + segmented pool reduction (batch sorted -> few runs)
    {
        int c = tid & 127, part = tid >> 7;
        int d0 = part * 8, d1 = min(d0 + 8, nodes);
        float sum = 0.f; int cg = -1;
        for (int dl = d0; dl < d1; ++dl) {
            float v = lrelu(acc[c][dl] / dvs[c >> 5][dl] + bias[c], 0.01f);
            int g = gb[dl];
            if (g != cg) {
                if (cg >= 0) atomicAdd(pool + (size_t)cg * F_DIM + c, sum);
                sum = 0.f; cg = g;
            }
            sum += v;
        }
        if (cg >= 0) atomicAdd(pool + (size_t)cg * F_DIM + c, sum);
    }
}

// ---------------------------------------------------------------------------
// branch fc, both channels (128 blocks): node count per graph via binary
// search on the SORTED batch array (atomic-free), then 128x128 mat-vec.
__global__ void branch_fc2(const float* __restrict__ pool0, const float* __restrict__ pool1,
                           const int* __restrict__ batch0, const int* __restrict__ batch1,
                           const float* __restrict__ W0, const float* __restrict__ b0,
                           const float* __restrict__ W1, const float* __restrict__ b1,
                           float* __restrict__ out0, float* __restrict__ out1, int n) {
    int ch = blockIdx.x >> 6;
    int g  = blockIdx.x & 63;
    const float* pool  = ch ? pool1 : pool0;
    const int*   batch = ch ? batch1 : batch0;
    const float* W     = ch ? W1 : W0;
    const float* b     = ch ? b1 : b0;
    float*       out   = ch ? out1 : out0;

    int lo = lower_bound_i(batch, n, g);
    int hi = lower_bound_i(batch, n, g + 1);
    float c = fmaxf((float)(hi - lo), 1.f);

    __shared__ float xm[F_DIM];
    int j = threadIdx.x;  // 128 threads
    xm[j] = pool[(size_t)g * F_DIM + j] / c;
    __syncthreads();
    float acc = b[j];
    for (int k = 0; k < F_DIM; ++k) acc += xm[k] * W[k * F_DIM + j];
    out[(size_t)g * F_DIM + j] = lrelu(acc, 0.01f);
}

// ---------------------------------------------------------------------------
// head: xc = concat(x1,x2); fc1+lrelu; fc2+lrelu; out
__global__ void head_k(const float* __restrict__ x1, const float* __restrict__ x2,
                       const float* __restrict__ W1, const float* __restrict__ b1,
                       const float* __restrict__ W2, const float* __restrict__ b2,
                       const float* __restrict__ Wo, const float* __restrict__ bo,
                       float* __restrict__ out) {
    int g = blockIdx.x;
    int t = threadIdx.x;  // 256 threads
    __shared__ float xc[2 * F_DIM];
    __shared__ float h1[F_DIM];
    __shared__ float h2[16];
    xc[t] = (t < F_DIM) ? x1[(size_t)g * F_DIM + t] : x2[(size_t)g * F_DIM + (t - F_DIM)];
    __syncthreads();
    if (t < F_DIM) {
        float acc = b1[t];
        for (int k = 0; k < 2 * F_DIM; ++k) acc += xc[k] * W1[k * F_DIM + t];
        h1[t] = lrelu(acc, 0.01f);
    }
    __syncthreads();
    if (t < 16) {
        float acc = b2[t];
        for (int k = 0; k < F_DIM; ++k) acc += h1[k] * W2[k * 16 + t];
        h2[t] = lrelu(acc, 0.01f);
    }
    __syncthreads();
    if (t == 0) {
        float acc = bo[0];
        for (int k = 0; k < 16; ++k) acc += h2[k] * Wo[k];
        out[g] = acc;
    }
}

// ---------------------------------------------------------------------------
extern "C" void kernel_launch(void* const* d_in, const int* in_sizes, int n_in,
                              void* d_out, int out_size, void* d_ws, size_t ws_size,
                              hipStream_t stream) {
    const int N = in_sizes[0] / F_DIM;   // 50000
    const int E = in_sizes[1] / 2;       // 800000
    const int TOT = E + N;

    const int* ei0    = (const int*)d_in[1];
    const int* ei1    = (const int*)d_in[4];
    const int* batch0 = (const int*)d_in[2];
    const int* batch1 = (const int*)d_in[5];

    // workspace layout
    float* w = (float*)d_ws;
    size_t off = 0;
    float* xl   = w + off; off += (size_t)N * F_DIM;      // shared between channels
    float* xr   = w + off; off += (size_t)N * F_DIM;
    float* xfc0 = w + off; off += (size_t)B_GRAPHS * F_DIM;
    float* xfc1 = w + off; off += (size_t)B_GRAPHS * F_DIM;
    int* ss0    = (int*)(w + off); off += (size_t)TOT;
    int* ss1    = (int*)(w + off); off += (size_t)TOT;
    int* st0    = (int*)(w + off); off += (size_t)(N + 1);
    int* st1    = (int*)(w + off); off += (size_t)(N + 1);
    // contiguous zero-region: pool0 | pool1 | cnt0 | cnt1
    float* pool0 = w + off;
    float* pool1 = pool0 + (size_t)B_GRAPHS * F_DIM;
    int*   cnt0  = (int*)(pool1 + (size_t)B_GRAPHS * F_DIM);
    int*   cnt1  = cnt0 + N;
    const size_t zeroBytes = (2 * (size_t)B_GRAPHS * F_DIM + 2 * (size_t)N) * 4;

    const int edgeBlocks = (E + 255) / 256;
    const int gemmBlocks = (N + 15) / 16;   // 3125
    const int aggBlocks  = (N + AGG_NODES - 1) / AGG_NODES;   // 1563
    const int ipb = (2 * TOT + gemmBlocks - 1) / gemmBlocks;  // 544

    hipMemsetAsync(pool0, 0, zeroBytes, stream);
    hipLaunchKernelGGL(count2_k, dim3(edgeBlocks, 2), dim3(256), 0, stream,
                       ei0, ei1, cnt0, cnt1, E);
    hipLaunchKernelGGL(scan2_k, dim3(2), dim3(1024), 0, stream,
                       cnt0, cnt1, st0, st1, N, TOT);

    // channel 0: GEMM + both channels' scatter, then aggregation
    hipLaunchKernelGGL(gemm2_bias_scatter, dim3(gemmBlocks), dim3(256), 0, stream,
                       (const float*)d_in[0],
                       (const float*)d_in[6], (const float*)d_in[7],
                       (const float*)d_in[8], (const float*)d_in[9],
                       xl, xr, N,
                       ei0, ei1, st0, st1, cnt0, cnt1, ss0, ss1, E, TOT, ipb);
    hipLaunchKernelGGL(gat_agg_v9, dim3(aggBlocks), dim3(512), 0, stream,
                       xl, xr, (const float*)d_in[10], (const float*)d_in[11],
                       st0, ss0, batch0, pool0, N);

    // channel 1
    hipLaunchKernelGGL(gemm2_bias, dim3(gemmBlocks), dim3(256), 0, stream,
                       (const float*)d_in[3],
                       (const float*)d_in[14], (const float*)d_in[15],
                       (const float*)d_in[16], (const float*)d_in[17],
                       xl, xr, N);
    hipLaunchKernelGGL(gat_agg_v9, dim3(aggBlocks), dim3(512), 0, stream,
                       xl, xr, (const float*)d_in[18], (const float*)d_in[19],
                       st1, ss1, batch1, pool1, N);

    hipLaunchKernelGGL(branch_fc2, dim3(2 * B_GRAPHS), dim3(F_DIM), 0, stream,
                       pool0, pool1, batch0, batch1,
                       (const float*)d_in[12], (const float*)d_in[13],
                       (const float*)d_in[20], (const float*)d_in[21],
                       xfc0, xfc1, N);

    hipLaunchKernelGGL(head_k, dim3(B_GRAPHS), dim3(256), 0, stream,
                       xfc0, xfc1,
                       (const float*)d_in[22], (const float*)d_in[23],
                       (const float*)d_in[24], (const float*)d_in[25],
                       (const float*)d_in[26], (const float*)d_in[27],
                       (float*)d_out);
}